// Round 14
// baseline (1089.715 us; speedup 1.0000x reference)
//
#include <hip/hip_runtime.h>

#define NN 8192
#define TK 128
#define KNNK 32
#define CAP 320
#define CSTR 321   // stride ≡ 1 (mod 32): rows land in different banks

typedef unsigned long long u64;
typedef long long i64;
typedef unsigned int u32;
typedef unsigned short u16;
typedef _Float16 f16;
typedef __attribute__((ext_vector_type(8))) _Float16 half8;
typedef __attribute__((ext_vector_type(4))) float f32x4;

// ws layout:
// [0,8MB)      f2p interleaved planes: f16 [2][16kg][8192][16]  ([0..7]=hi, [8..15]=lo*2^10)
// [8MB,12MB)   ws_h : f16 [2][8192][128]
// [12MB,16MB)  ws_kin: f16x4 packed as uint2 [2][8192][32]
// [16MB,+576)  stats u64[72]; [16MB+1KB) fstats f32[64]

union HU { u16 u; f16 f; };
__device__ __forceinline__ u16 f2h_bits(float v){ HU h; h.f = (f16)v; return h.u; }
__device__ __forceinline__ float h2f(u16 u){ HU h; h.u = u; return (float)h.f; }

__device__ __forceinline__ u32 f2key(float v){
    u32 u = __float_as_uint(v);
    return u ^ ((u32)((int)u >> 31) | 0x80000000u);
}
__device__ __forceinline__ float key2f(u32 k){
    u32 u = (k & 0x80000000u) ? (k ^ 0x80000000u) : ~k;
    return __uint_as_float(u);
}

// ---------------- K0: zero stat accumulators ----------------
__global__ void k0_zero(u64* __restrict__ stats){
    const int t = threadIdx.x;
    if (t < 72) stats[t] = 0ull;
}

// ---------------- K0b: pack fmap2 -> interleaved fp16 hi|lo records ----------------
__global__ __launch_bounds__(256) void k0b_pack(const float* __restrict__ src,
                                                f16* __restrict__ pl){
    const int tid = blockIdx.x*256 + threadIdx.x;       // [0, 262144)
    const int n  = tid & (NN-1);
    const int kg = (tid >> 13) & 15;
    const int b  = tid >> 17;
    const float* s = src + ((size_t)(b*128 + kg*8))*NN + n;
    u32 hw[4], lw[4];
    #pragma unroll
    for (int p=0; p<4; ++p){
        const float v0 = s[(2*p  )*NN], v1 = s[(2*p+1)*NN];
        const u16 h0 = f2h_bits(v0), h1 = f2h_bits(v1);
        const float r0 = (v0 - h2f(h0))*1024.f, r1 = (v1 - h2f(h1))*1024.f;
        hw[p] = (u32)h0 | ((u32)h1 << 16);
        lw[p] = (u32)f2h_bits(r0) | ((u32)f2h_bits(r1) << 16);
    }
    const size_t o = 2*((size_t)(b*16 + kg)*NN + n);    // uint4 index
    ((uint4*)pl)[o]   = make_uint4(hw[0],hw[1],hw[2],hw[3]);
    ((uint4*)pl)[o+1] = make_uint4(lw[0],lw[1],lw[2],lw[3]);
}

#define MFMA16(a,b,c) __builtin_amdgcn_mfma_f32_16x16x32_f16(a,b,c,0,0,0)

// ---------------- K1: MFMA corr + filter + bit-descent select + vox + knn + h ----------------
// 512 threads, 32 rows/block, r11-level per-thread state (two passes of 16 rows),
// 72.7KB LDS + 128-reg budget -> 2 blocks/CU.
__global__ __launch_bounds__(512, 4) void k1_corr_topk(
    const float* __restrict__ fmap1, const f16* __restrict__ f2p,
    const float* __restrict__ xyz2, const float* __restrict__ coords,
    const float* __restrict__ w1, const float* __restrict__ b1,
    u16* __restrict__ wsh, uint2* __restrict__ wskin, u64* __restrict__ stats)
{
    __shared__ union {
        struct { u32 keyhi[32][CSTR]; u16 kcol[32][CSTR]; } sel;  // 61632 B
        float w1s[128*81];                                        // 41472 B (select space dead)
    } up;
    __shared__ u32   vboth[32][81];       // 10368 B: count<<24 | sum(val*2^13); reused as voxn f32
    __shared__ int   ccnt[32];
    __shared__ float rsig[32];            // per-row corr sigma = ||f1_row||/sqrt(128)
    __shared__ u64   wgo[8], wgq[8], wk1[4], wk2[16];

    const int t = threadIdx.x;
    const int lane = t & 63, wv = t >> 6;   // 8 waves
    const int blk = blockIdx.x;
    const int b = (blk >> 2) & 1;
    const int i0 = (((blk & 3) << 6) | (blk >> 3)) * 32;

    if (t < 32) ccnt[t] = 0;
    if (t < 8){ wgo[t]=0ull; wgq[t]=0ull; }
    if (t < 4) wk1[t]=0ull;
    if (t < 16) wk2[t]=0ull;
    for (int z=t; z<32*81; z+=512) ((u32*)vboth)[z]=0u;

    const float scl = 0.08838834764831845f;  // 1/sqrt(128)

    // ---- A fragments: 2 row-groups x 4 K-steps, hi + scaled-lo (fp16) + row norms ----
    half8 Ah[2][4], Al[2][4];
    float nrm[2] = {0.f, 0.f};
    const float* f1b = fmap1 + (size_t)b*128*NN;
    #pragma unroll
    for (int g=0; g<2; ++g){
        const int row = i0 + g*16 + (lane & 15);
        #pragma unroll
        for (int s=0; s<4; ++s){
            const int kb = s*32 + (lane>>4)*8;
            #pragma unroll
            for (int j=0; j<8; ++j){
                const float v = f1b[(size_t)(kb+j)*NN + row];
                const f16 h = (f16)v;
                Ah[g][s][j] = h;
                Al[g][s][j] = (f16)((v - (float)h)*1024.f);
                nrm[g] = fmaf(v, v, nrm[g]);
            }
        }
    }
    #pragma unroll
    for (int g=0; g<2; ++g){
        nrm[g] += __shfl_xor(nrm[g], 16);
        nrm[g] += __shfl_xor(nrm[g], 32);   // all 4 k-group lanes combined
    }
    if (wv == 0 && lane < 16){
        rsig[lane]      = fmaxf(sqrtf(nrm[0])*scl, 1e-20f);
        rsig[16 + lane] = fmaxf(sqrtf(nrm[1])*scl, 1e-20f);
    }
    __syncthreads();

    // per-thread RAW threshold (pre-divided by scl): accept iff raw > rthr
    float rthr[2][4];
    #pragma unroll
    for (int g=0; g<2; ++g)
        #pragma unroll
        for (int q=0; q<4; ++q)
            rthr[g][q] = 1.9f * rsig[g*16 + (lane>>4)*4 + q] / scl;

    // ---- MFMA GEMM: 16 chunks of 512 cols; 8 waves x 64 cols (4 serialized tiles) ----
    const f16* Bp = f2p + (size_t)b*16*NN*16;
    for (int ch=0; ch<16; ++ch){
        const int colbase = ch*512 + wv*64;
        #pragma unroll
        for (int tl=0; tl<4; ++tl){
            f32x4 Cm0=(f32x4)0.f, Cm1=(f32x4)0.f, Cl0=(f32x4)0.f, Cl1=(f32x4)0.f;
            const int col = colbase + tl*16 + (lane & 15);
            #pragma unroll
            for (int s=0; s<4; ++s){
                const int kg = s*4 + (lane>>4);
                const size_t off = ((size_t)kg*NN + col)*16;
                const half8 bh = *(const half8*)(Bp + off);
                const half8 bl = *(const half8*)(Bp + off + 8);
                Cm0 = MFMA16(Ah[0][s], bh, Cm0);
                Cl0 = MFMA16(Al[0][s], bh, Cl0);
                Cl0 = MFMA16(Ah[0][s], bl, Cl0);
                Cm1 = MFMA16(Ah[1][s], bh, Cm1);
                Cl1 = MFMA16(Al[1][s], bh, Cl1);
                Cl1 = MFMA16(Ah[1][s], bl, Cl1);
            }
            #pragma unroll
            for (int q=0; q<4; ++q){
                const float r0 = fmaf(Cl0[q], (1.f/1024.f), Cm0[q]);
                if (r0 > rthr[0][q]){
                    const int r = (lane>>4)*4 + q;
                    const int slot = atomicAdd(&ccnt[r], 1);
                    if (slot < CAP){ up.sel.keyhi[r][slot] = f2key(r0*scl); up.sel.kcol[r][slot] = (u16)col; }
                }
                const float r1 = fmaf(Cl1[q], (1.f/1024.f), Cm1[q]);
                if (r1 > rthr[1][q]){
                    const int r = 16 + (lane>>4)*4 + q;
                    const int slot = atomicAdd(&ccnt[r], 1);
                    if (slot < CAP){ up.sel.keyhi[r][slot] = f2key(r1*scl); up.sel.kcol[r][slot] = (u16)col; }
                }
            }
        }
    }
    __syncthreads();

    // ---- exact select: bit-descent + scan compaction + rerank; 2 passes of 16 rows,
    //      32 lockstep threads/row (r11-proven register footprint) ----
    for (int half=0; half<2; ++half){
        const int r = (t >> 5) + half*16;
        const int s = t & 31;
        const int cnt = min(ccnt[r], CAP);
        u64 mkey[10];
        #pragma unroll
        for (int u=0; u<10; ++u){
            const int idx = s + (u<<5);
            const u32 kh = up.sel.keyhi[r][idx];
            const u32 cl = up.sel.kcol[r][idx];
            const u64 k = ((u64)kh << 13) | (u64)(8191 - (int)cl);
            mkey[u] = (idx < cnt) ? k : 0ull;   // valid keys have bit 44 set (val>0)
        }
        // T := exact 128th-largest key via 44-step bit descent
        u64 T = 1ull << 44;
        for (int bit = 43; bit >= 0; --bit){
            const u64 cand = T | (1ull << bit);
            int c = 0;
            #pragma unroll
            for (int u=0; u<10; ++u) c += (mkey[u] >= cand) ? 1 : 0;
            c += __shfl_xor(c, 1); c += __shfl_xor(c, 2); c += __shfl_xor(c, 4);
            c += __shfl_xor(c, 8); c += __shfl_xor(c, 16);
            if (c >= TK) T = cand;
        }
        // compact the exactly-128 keys >= T via 32-wide exclusive scan (no atomics)
        int mycnt = 0;
        #pragma unroll
        for (int u=0; u<10; ++u) mycnt += (mkey[u] >= T) ? 1 : 0;
        int pre = mycnt;
        #pragma unroll
        for (int off=1; off<32; off<<=1){
            const int v = __shfl_up(pre, off, 32);
            if (s >= off) pre += v;
        }
        int base = pre - mycnt;
        #pragma unroll
        for (int u=0; u<10; ++u){
            if (mkey[u] >= T){
                up.sel.keyhi[r][base] = (u32)(mkey[u] >> 13);
                up.sel.kcol[r][base]  = (u16)(8191 - (int)(mkey[u] & 8191u));
                ++base;
            }
        }
        // rerank the 128 into exact (val desc, col asc) order (wave-internal ordering)
        u64 rk[4]; int rr[4];
        #pragma unroll
        for (int u2=0; u2<4; ++u2){
            const int idx = s + (u2<<5);
            rk[u2] = ((u64)up.sel.keyhi[r][idx] << 13) | (u64)(8191 - (int)up.sel.kcol[r][idx]);
            rr[u2] = 0;
        }
        for (int j=0; j<TK; ++j){
            const u64 kj = ((u64)up.sel.keyhi[r][j] << 13) | (u64)(8191 - (int)up.sel.kcol[r][j]);
            #pragma unroll
            for (int u2=0; u2<4; ++u2) rr[u2] += (kj > rk[u2]) ? 1 : 0;
        }
        #pragma unroll
        for (int u2=0; u2<4; ++u2){
            up.sel.keyhi[r][rr[u2]] = (u32)(rk[u2] >> 13);
            up.sel.kcol[r][rr[u2]]  = (u16)(8191 - (int)(rk[u2] & 8191u));
        }
    }
    __syncthreads();

    // ---- phases V+K: 2 passes of 16 rows, 32 thr/row, 4 candidates/thread ----
    for (int half=0; half<2; ++half){
        const int r = (t >> 5) + half*16;
        const int s = t & 31;
        const int i = i0 + r;
        const float cx = coords[((size_t)b*NN + i)*3 + 0];
        const float cy = coords[((size_t)b*NN + i)*3 + 1];
        const float cz = coords[((size_t)b*NN + i)*3 + 2];
        float wdx[4], wdy[4], wdz[4], wvl[4], wdist[4];
        #pragma unroll
        for (int u=0; u<4; ++u){
            const int w = s + (u<<5);
            const u32 kh = up.sel.keyhi[r][w];
            const int col = (int)up.sel.kcol[r][w];
            const float val = key2f(kh);
            const float* pp = xyz2 + ((size_t)b*NN + col)*3;
            const float dx = pp[0]-cx, dy = pp[1]-cy, dz = pp[2]-cz;
            wdist[u] = dx*dx + dy*dy + dz*dz;
            wdx[u]=dx; wdy[u]=dy; wdz[u]=dz; wvl[u]=val;
            #pragma unroll
            for (int lvl=0; lvl<3; ++lvl){
                const float rs = 0.25f * (float)(1<<lvl);
                const float fx = rintf(dx/rs), fy = rintf(dy/rs), fz = rintf(dz/rs);
                if (fabsf(fx)<=1.f && fabsf(fy)<=1.f && fabsf(fz)<=1.f){
                    const int bin = lvl*27 + ((int)fx+1)*9 + ((int)fy+1)*3 + ((int)fz+1);
                    // count in bits 24+, sum(val*2^13) in bits 0-23 (vals>0; 128*8*8192 < 2^24)
                    atomicAdd(&vboth[r][bin], (1u<<24) | (u32)lrintf(val*8192.f));
                }
            }
        }
        // knn rank via half-wave broadcast (rows are 32-lane groups)
        const int rbase = lane & 32;
        int rank[4] = {0,0,0,0};
        #pragma unroll
        for (int u2=0; u2<4; ++u2){
            #pragma unroll
            for (int jj=0; jj<32; ++jj){
                const float o = __shfl(wdist[u2], rbase + jj);
                const int j = jj + (u2<<5);
                #pragma unroll
                for (int u=0; u<4; ++u)
                    rank[u] += (o < wdist[u] || (o == wdist[u] && j < s + (u<<5))) ? 1 : 0;
            }
        }
        float m1[4] = {0.f,0.f,0.f,0.f};
        float m2[16];
        #pragma unroll
        for (int q=0;q<16;q++) m2[q]=0.f;
        #pragma unroll
        for (int u=0; u<4; ++u){
            if (rank[u] < KNNK){
                const float kv[4] = {wvl[u], wdx[u], wdy[u], wdz[u]};
                uint2 kw;
                kw.x = (u32)f2h_bits(kv[0]) | ((u32)f2h_bits(kv[1]) << 16);
                kw.y = (u32)f2h_bits(kv[2]) | ((u32)f2h_bits(kv[3]) << 16);
                wskin[((size_t)b*NN + i)*KNNK + rank[u]] = kw;
                #pragma unroll
                for (int a2=0;a2<4;a2++){
                    m1[a2] += kv[a2];
                    #pragma unroll
                    for (int b2=0;b2<4;b2++) m2[a2*4+b2] += kv[a2]*kv[b2];
                }
            }
        }
        #pragma unroll
        for (int q=0; q<20; ++q){
            i64 v = llrintf(((q<4) ? m1[q] : m2[q-4]) * 1048576.f);
            #pragma unroll
            for (int off=1; off<64; off<<=1) v += __shfl_xor(v, off);
            if (lane == 0){
                if (q < 4) atomicAdd(&wk1[q], (u64)v);
                else       atomicAdd(&wk2[q-4], (u64)v);
            }
        }
    }
    __syncthreads();

    // ---- w1 -> LDS (select space dead) + voxn finalize (in-place) ----
    for (int idx=t; idx<128*81; idx+=512) up.w1s[idx] = w1[idx];
    for (int z=t; z<32*81; z+=512){
        const u32 k = ((u32*)vboth)[z];
        const float vv = (float)(k & 0xFFFFFFu) * (1.f/8192.f);
        const float c = fmaxf((float)(k >> 24), 1.f);
        ((float*)vboth)[z] = vv / c;
    }
    __syncthreads();

    // ---- phase H: h = b1 + w1*voxn ; store f16 ; group stats ----
    {
        const int r = t >> 4, cg = t & 15;   // 32 rows x 16 channel-groups of 8
        const int i = i0 + r;
        const float* voxnp = (const float*)&vboth[0][0];
        float h8[8];
        #pragma unroll
        for (int i2=0;i2<8;i2++) h8[i2] = b1[cg*8+i2];
        for (int j=0; j<81; ++j){
            const float vj = voxnp[r*81 + j];
            #pragma unroll
            for (int i2=0;i2<8;i2++) h8[i2] = fmaf(up.w1s[(cg*8+i2)*81 + j], vj, h8[i2]);
        }
        uint4 hv4;
        hv4.x = (u32)f2h_bits(h8[0]) | ((u32)f2h_bits(h8[1])<<16);
        hv4.y = (u32)f2h_bits(h8[2]) | ((u32)f2h_bits(h8[3])<<16);
        hv4.z = (u32)f2h_bits(h8[4]) | ((u32)f2h_bits(h8[5])<<16);
        hv4.w = (u32)f2h_bits(h8[6]) | ((u32)f2h_bits(h8[7])<<16);
        ((uint4*)wsh)[((size_t)(b*NN + i)*128 + cg*8) >> 3] = hv4;
        i64 s1 = 0, s2 = 0;
        #pragma unroll
        for (int i2=0;i2<8;i2++){
            s1 += llrintf(h8[i2]*1048576.f);
            s2 += llrintf(h8[i2]*h8[i2]*1048576.f);
        }
        s1 += __shfl_xor(s1, 1);  s2 += __shfl_xor(s2, 1);
        s1 += __shfl_xor(s1, 16); s2 += __shfl_xor(s2, 16);
        s1 += __shfl_xor(s1, 32); s2 += __shfl_xor(s2, 32);
        if (((lane & 1) == 0) && (lane >> 4) == 0){
            atomicAdd(&wgo[cg>>1], (u64)s1);
            atomicAdd(&wgq[cg>>1], (u64)s2);
        }
    }
    __syncthreads();

    if (t < 8){ atomicAdd(&stats[b*8 + t], wgo[t]); atomicAdd(&stats[16 + b*8 + t], wgq[t]); }
    if (t < 4){ atomicAdd(&stats[32 + b*4 + t], wk1[t]); }
    if (t < 16){ atomicAdd(&stats[40 + b*16 + t], wk2[t]); }
}

// ---------------- K2: finalize GN statistics ----------------
__global__ void k2_stats(const u64* __restrict__ stats, float* __restrict__ fstats,
                         const float* __restrict__ kcw, const float* __restrict__ kcb)
{
    const int t = threadIdx.x;
    if (t < 16){
        const double S = (double)(i64)stats[t];
        const double Q = (double)(i64)stats[16+t];
        const double cnt = 16.0*8192.0;
        const double mean = S / 1048576.0 / cnt;
        const double var  = Q / 1048576.0 / cnt - mean*mean;
        fstats[t]    = (float)mean;
        fstats[16+t] = (float)(1.0/sqrt(var + 1e-5));
    }
    if (t >= 32 && t < 48){
        const int u = t - 32;
        const int b = u >> 3, g = u & 7;
        double M1[4], M2[4][4];
        for (int a=0;a<4;a++) M1[a] = (double)(i64)stats[32 + b*4 + a] / 1048576.0;
        for (int a=0;a<4;a++) for (int c=0;c<4;c++)
            M2[a][c] = (double)(i64)stats[40 + b*16 + a*4 + c] / 1048576.0;
        const double cnt = 8192.0*32.0;
        double SUM=0.0, SSQ=0.0;
        for (int c = g*8; c < g*8+8; ++c){
            double wv[4]; for (int a=0;a<4;a++) wv[a] = (double)kcw[c*4+a];
            const double bc = (double)kcb[c];
            double sc = bc*cnt, qc = bc*bc*cnt;
            for (int a=0;a<4;a++){
                sc += wv[a]*M1[a];
                qc += 2.0*bc*wv[a]*M1[a];
                for (int e=0;e<4;e++) qc += wv[a]*wv[e]*M2[a][e];
            }
            SUM += sc; SSQ += qc;
        }
        const double denom = 8.0*cnt;
        const double mean = SUM/denom;
        const double var  = SSQ/denom - mean*mean;
        fstats[32+u] = (float)mean;
        fstats[48+u] = (float)(1.0/sqrt(var + 1e-5));
    }
}

// ---------------- K3a: GN + PReLU + W2 (vox branch) ----------------
__global__ __launch_bounds__(256) void k3a_vox(
    const u16* __restrict__ wsh, const float* __restrict__ fstats,
    const float* __restrict__ gnw, const float* __restrict__ gnb,
    const float* __restrict__ pr, const float* __restrict__ w2,
    const float* __restrict__ b2, float* __restrict__ out)
{
    __shared__ float p[16][128];
    __shared__ float w2s[64][129];
    const int t = threadIdx.x;
    const int base = blockIdx.x * 16;
    const int b = base >> 13;
    for (int u=t; u<64*128; u+=256) w2s[u>>7][u&127] = w2[u];
    const float a = pr[0];
    for (int u=t; u<16*128; u+=256){
        const int pt=u>>7, c=u&127, g=c>>4;
        const float hv = h2f(wsh[(size_t)(base+pt)*128 + c]);
        const float hn = (hv - fstats[b*8+g])*fstats[16+b*8+g]*gnw[c] + gnb[c];
        p[pt][c] = hn>=0.f ? hn : a*hn;
    }
    __syncthreads();
    const int o = t & 63, wv = t >> 6;
    float acc0=b2[o], acc1=acc0, acc2=acc0, acc3=acc0;
    for (int c=0;c<128;c++){
        const float w = w2s[o][c];
        acc0 = fmaf(w, p[wv*4+0][c], acc0);
        acc1 = fmaf(w, p[wv*4+1][c], acc1);
        acc2 = fmaf(w, p[wv*4+2][c], acc2);
        acc3 = fmaf(w, p[wv*4+3][c], acc3);
    }
    const float4 res = {acc0,acc1,acc2,acc3};
    *(float4*)&out[((size_t)b*64 + o)*NN + (base & (NN-1)) + wv*4] = res;
}

// ---------------- K3b: knn conv + GN + PReLU + maxpool + ko ----------------
__global__ __launch_bounds__(256) void k3b_knn(
    const uint2* __restrict__ wskin, const float* __restrict__ fstats,
    const float* __restrict__ kcw, const float* __restrict__ kcb,
    const float* __restrict__ gnw, const float* __restrict__ gnb,
    const float* __restrict__ pr, const float* __restrict__ kow,
    const float* __restrict__ kob, float* __restrict__ out)
{
    __shared__ float skin[16][KNNK*4+4];
    __shared__ float kml[16][65];
    __shared__ float kos[64][65];
    const int t = threadIdx.x;
    const int base = blockIdx.x * 16;
    const int b = base >> 13;
    for (int v=t; v<16*KNNK; v+=256){
        const int pt = v>>5, q = v&31;
        const uint2 kw = wskin[(size_t)(base+pt)*KNNK + q];
        skin[pt][q*4+0] = h2f((u16)(kw.x & 0xFFFF));
        skin[pt][q*4+1] = h2f((u16)(kw.x >> 16));
        skin[pt][q*4+2] = h2f((u16)(kw.y & 0xFFFF));
        skin[pt][q*4+3] = h2f((u16)(kw.y >> 16));
    }
    for (int u=t; u<4096; u+=256) kos[u>>6][u&63] = kow[u];
    __syncthreads();
    const float a = pr[0];
    {
        const int pt = t>>4, cb = (t&15)*4;
        #pragma unroll
        for (int cc=0; cc<4; ++cc){
            const int c = cb+cc, g = c>>3;
            const float mean = fstats[32+b*8+g], rstd = fstats[48+b*8+g];
            const float gw = rstd*gnw[c], gb = gnb[c]-mean*gw;
            const float w0=kcw[c*4], w1v=kcw[c*4+1], w2v=kcw[c*4+2], w3=kcw[c*4+3], bc=kcb[c];
            float mx = -3.0e38f;
            for (int kk=0;kk<KNNK;kk++){
                const float4 sv = *(const float4*)&skin[pt][kk*4];
                float kf = fmaf(w0,sv.x, fmaf(w1v,sv.y, fmaf(w2v,sv.z, fmaf(w3,sv.w, bc))));
                float hn = kf*gw + gb;
                hn = hn>=0.f ? hn : a*hn;
                mx = fmaxf(mx, hn);
            }
            kml[pt][c] = mx;
        }
    }
    __syncthreads();
    const int o = t & 63, wv = t >> 6;
    float acc0=kob[o], acc1=acc0, acc2=acc0, acc3=acc0;
    for (int c=0;c<64;c++){
        const float w = kos[o][c];
        acc0 = fmaf(w, kml[wv*4+0][c], acc0);
        acc1 = fmaf(w, kml[wv*4+1][c], acc1);
        acc2 = fmaf(w, kml[wv*4+2][c], acc2);
        acc3 = fmaf(w, kml[wv*4+3][c], acc3);
    }
    float* op = &out[((size_t)b*64 + o)*NN + (base & (NN-1)) + wv*4];
    float4 cur = *(float4*)op;
    cur.x += acc0; cur.y += acc1; cur.z += acc2; cur.w += acc3;
    *(float4*)op = cur;
}

extern "C" void kernel_launch(void* const* d_in, const int* in_sizes, int n_in,
                              void* d_out, int out_size, void* d_ws, size_t ws_size,
                              hipStream_t stream)
{
    const float* fmap1   = (const float*)d_in[0];
    const float* fmap2   = (const float*)d_in[1];
    const float* xyz2    = (const float*)d_in[2];
    const float* coords  = (const float*)d_in[3];
    const float* oc_w1   = (const float*)d_in[4];
    const float* oc_b1   = (const float*)d_in[5];
    const float* oc_gn_w = (const float*)d_in[6];
    const float* oc_gn_b = (const float*)d_in[7];
    const float* oc_pr   = (const float*)d_in[8];
    const float* oc_w2   = (const float*)d_in[9];
    const float* oc_b2   = (const float*)d_in[10];
    const float* kc_w    = (const float*)d_in[11];
    const float* kc_b    = (const float*)d_in[12];
    const float* kc_gn_w = (const float*)d_in[13];
    const float* kc_gn_b = (const float*)d_in[14];
    const float* kc_pr   = (const float*)d_in[15];
    const float* ko_w    = (const float*)d_in[16];
    const float* ko_b    = (const float*)d_in[17];

    char* ws = (char*)d_ws;
    f16*   f2p    = (f16*)ws;
    u16*   wsh    = (u16*)(ws + (size_t)8*1024*1024);
    uint2* wskin  = (uint2*)(ws + (size_t)12*1024*1024);
    u64*   stats  = (u64*) (ws + (size_t)16*1024*1024);
    float* fstats = (float*)(ws + (size_t)16*1024*1024 + 1024);
    float* out    = (float*)d_out;

    k0_zero<<<dim3(1), dim3(128), 0, stream>>>(stats);
    k0b_pack<<<dim3(1024), dim3(256), 0, stream>>>(fmap2, f2p);
    k1_corr_topk<<<dim3(512), dim3(512), 0, stream>>>(
        fmap1, f2p, xyz2, coords, oc_w1, oc_b1, wsh, wskin, stats);
    k2_stats<<<dim3(1), dim3(64), 0, stream>>>(stats, fstats, kc_w, kc_b);
    k3a_vox<<<dim3(1024), dim3(256), 0, stream>>>(
        wsh, fstats, oc_gn_w, oc_gn_b, oc_pr, oc_w2, oc_b2, out);
    k3b_knn<<<dim3(1024), dim3(256), 0, stream>>>(
        wskin, fstats, kc_w, kc_b, kc_gn_w, kc_gn_b, kc_pr, ko_w, ko_b, out);
}

// Round 15
// 808.604 us; speedup vs baseline: 1.3477x; 1.3477x over previous
//
#include <hip/hip_runtime.h>

#define NN 8192
#define TK 128
#define KNNK 32
#define CAP 320
#define CSTR 321   // stride ≡ 1 (mod 32): rows land in different banks

typedef unsigned long long u64;
typedef long long i64;
typedef unsigned int u32;
typedef unsigned short u16;
typedef _Float16 f16;
typedef __attribute__((ext_vector_type(8))) _Float16 half8;
typedef __attribute__((ext_vector_type(4))) float f32x4;

// ws layout:
// [0,8MB)      f2p interleaved planes: f16 [2][16kg][8192][16]  ([0..7]=hi, [8..15]=lo*2^10)
// [8MB,12MB)   ws_h : f16 [2][8192][128]
// [12MB,16MB)  ws_kin: f16x4 packed as uint2 [2][8192][32]
// [16MB,+576)  stats u64[72]; [16MB+1KB) fstats f32[64]

union HU { u16 u; f16 f; };
__device__ __forceinline__ u16 f2h_bits(float v){ HU h; h.f = (f16)v; return h.u; }
__device__ __forceinline__ float h2f(u16 u){ HU h; h.u = u; return (float)h.f; }

__device__ __forceinline__ u32 f2key(float v){
    u32 u = __float_as_uint(v);
    return u ^ ((u32)((int)u >> 31) | 0x80000000u);
}
__device__ __forceinline__ float key2f(u32 k){
    u32 u = (k & 0x80000000u) ? (k ^ 0x80000000u) : ~k;
    return __uint_as_float(u);
}

// ---------------- K0: zero stat accumulators ----------------
__global__ void k0_zero(u64* __restrict__ stats){
    const int t = threadIdx.x;
    if (t < 72) stats[t] = 0ull;
}

// ---------------- K0b: pack fmap2 -> interleaved fp16 hi|lo records ----------------
__global__ __launch_bounds__(256) void k0b_pack(const float* __restrict__ src,
                                                f16* __restrict__ pl){
    const int tid = blockIdx.x*256 + threadIdx.x;       // [0, 262144)
    const int n  = tid & (NN-1);
    const int kg = (tid >> 13) & 15;
    const int b  = tid >> 17;
    const float* s = src + ((size_t)(b*128 + kg*8))*NN + n;
    u32 hw[4], lw[4];
    #pragma unroll
    for (int p=0; p<4; ++p){
        const float v0 = s[(2*p  )*NN], v1 = s[(2*p+1)*NN];
        const u16 h0 = f2h_bits(v0), h1 = f2h_bits(v1);
        const float r0 = (v0 - h2f(h0))*1024.f, r1 = (v1 - h2f(h1))*1024.f;
        hw[p] = (u32)h0 | ((u32)h1 << 16);
        lw[p] = (u32)f2h_bits(r0) | ((u32)f2h_bits(r1) << 16);
    }
    const size_t o = 2*((size_t)(b*16 + kg)*NN + n);    // uint4 index
    ((uint4*)pl)[o]   = make_uint4(hw[0],hw[1],hw[2],hw[3]);
    ((uint4*)pl)[o+1] = make_uint4(lw[0],lw[1],lw[2],lw[3]);
}

#define MFMA16(a,b,c) __builtin_amdgcn_mfma_f32_16x16x32_f16(a,b,c,0,0,0)

// ---------------- K1: MFMA corr + filter + bit-descent select + vox + knn + h ----------------
// 512 threads, 32 rows/block, relaxed 256-reg budget (actual usage ~<=128 -> 2 blocks/CU
// under 72.7KB LDS without compiler-induced spills).
__global__ __launch_bounds__(512, 2) void k1_corr_topk(
    const float* __restrict__ fmap1, const f16* __restrict__ f2p,
    const float* __restrict__ xyz2, const float* __restrict__ coords,
    const float* __restrict__ w1, const float* __restrict__ b1,
    u16* __restrict__ wsh, uint2* __restrict__ wskin, u64* __restrict__ stats)
{
    __shared__ union {
        struct { u32 keyhi[32][CSTR]; u16 kcol[32][CSTR]; } sel;  // 61632 B
        float w1s[128*81];                                        // 41472 B (select space dead)
    } up;
    __shared__ u32   vboth[32][81];       // 10368 B: count<<24 | sum(val*2^13); reused as voxn f32
    __shared__ int   ccnt[32];
    __shared__ float rsig[32];            // per-row corr sigma = ||f1_row||/sqrt(128)
    __shared__ u64   wgo[8], wgq[8], wk1[4], wk2[16];

    const int t = threadIdx.x;
    const int lane = t & 63, wv = t >> 6;   // 8 waves
    const int blk = blockIdx.x;
    const int b = (blk >> 2) & 1;
    const int i0 = (((blk & 3) << 6) | (blk >> 3)) * 32;

    if (t < 32) ccnt[t] = 0;
    if (t < 8){ wgo[t]=0ull; wgq[t]=0ull; }
    if (t < 4) wk1[t]=0ull;
    if (t < 16) wk2[t]=0ull;
    for (int z=t; z<32*81; z+=512) ((u32*)vboth)[z]=0u;

    const float scl = 0.08838834764831845f;  // 1/sqrt(128)

    // ---- A fragments: 2 row-groups x 4 K-steps, hi + scaled-lo (fp16) + row norms ----
    half8 Ah[2][4], Al[2][4];
    float nrm[2] = {0.f, 0.f};
    const float* f1b = fmap1 + (size_t)b*128*NN;
    #pragma unroll
    for (int g=0; g<2; ++g){
        const int row = i0 + g*16 + (lane & 15);
        #pragma unroll
        for (int s=0; s<4; ++s){
            const int kb = s*32 + (lane>>4)*8;
            #pragma unroll
            for (int j=0; j<8; ++j){
                const float v = f1b[(size_t)(kb+j)*NN + row];
                const f16 h = (f16)v;
                Ah[g][s][j] = h;
                Al[g][s][j] = (f16)((v - (float)h)*1024.f);
                nrm[g] = fmaf(v, v, nrm[g]);
            }
        }
    }
    #pragma unroll
    for (int g=0; g<2; ++g){
        nrm[g] += __shfl_xor(nrm[g], 16);
        nrm[g] += __shfl_xor(nrm[g], 32);   // all 4 k-group lanes combined
    }
    if (wv == 0 && lane < 16){
        rsig[lane]      = fmaxf(sqrtf(nrm[0])*scl, 1e-20f);
        rsig[16 + lane] = fmaxf(sqrtf(nrm[1])*scl, 1e-20f);
    }
    __syncthreads();

    // per-thread RAW threshold (pre-divided by scl): accept iff raw > rthr
    float rthr[2][4];
    #pragma unroll
    for (int g=0; g<2; ++g)
        #pragma unroll
        for (int q=0; q<4; ++q)
            rthr[g][q] = 1.9f * rsig[g*16 + (lane>>4)*4 + q] / scl;

    // ---- MFMA GEMM: 16 chunks of 512 cols; 8 waves x 64 cols (4 serialized tiles) ----
    const f16* Bp = f2p + (size_t)b*16*NN*16;
    for (int ch=0; ch<16; ++ch){
        const int colbase = ch*512 + wv*64;
        #pragma unroll
        for (int tl=0; tl<4; ++tl){
            f32x4 Cm0=(f32x4)0.f, Cm1=(f32x4)0.f, Cl0=(f32x4)0.f, Cl1=(f32x4)0.f;
            const int col = colbase + tl*16 + (lane & 15);
            #pragma unroll
            for (int s=0; s<4; ++s){
                const int kg = s*4 + (lane>>4);
                const size_t off = ((size_t)kg*NN + col)*16;
                const half8 bh = *(const half8*)(Bp + off);
                const half8 bl = *(const half8*)(Bp + off + 8);
                Cm0 = MFMA16(Ah[0][s], bh, Cm0);
                Cl0 = MFMA16(Al[0][s], bh, Cl0);
                Cl0 = MFMA16(Ah[0][s], bl, Cl0);
                Cm1 = MFMA16(Ah[1][s], bh, Cm1);
                Cl1 = MFMA16(Al[1][s], bh, Cl1);
                Cl1 = MFMA16(Ah[1][s], bl, Cl1);
            }
            #pragma unroll
            for (int q=0; q<4; ++q){
                const float r0 = fmaf(Cl0[q], (1.f/1024.f), Cm0[q]);
                if (r0 > rthr[0][q]){
                    const int r = (lane>>4)*4 + q;
                    const int slot = atomicAdd(&ccnt[r], 1);
                    if (slot < CAP){ up.sel.keyhi[r][slot] = f2key(r0*scl); up.sel.kcol[r][slot] = (u16)col; }
                }
                const float r1 = fmaf(Cl1[q], (1.f/1024.f), Cm1[q]);
                if (r1 > rthr[1][q]){
                    const int r = 16 + (lane>>4)*4 + q;
                    const int slot = atomicAdd(&ccnt[r], 1);
                    if (slot < CAP){ up.sel.keyhi[r][slot] = f2key(r1*scl); up.sel.kcol[r][slot] = (u16)col; }
                }
            }
        }
    }
    __syncthreads();

    // ---- exact select: bit-descent + scan compaction + rerank; 2 passes of 16 rows,
    //      32 lockstep threads/row (r11-proven register footprint) ----
    for (int half=0; half<2; ++half){
        const int r = (t >> 5) + half*16;
        const int s = t & 31;
        const int cnt = min(ccnt[r], CAP);
        u64 mkey[10];
        #pragma unroll
        for (int u=0; u<10; ++u){
            const int idx = s + (u<<5);
            const u32 kh = up.sel.keyhi[r][idx];
            const u32 cl = up.sel.kcol[r][idx];
            const u64 k = ((u64)kh << 13) | (u64)(8191 - (int)cl);
            mkey[u] = (idx < cnt) ? k : 0ull;   // valid keys have bit 44 set (val>0)
        }
        // T := exact 128th-largest key via 44-step bit descent
        u64 T = 1ull << 44;
        for (int bit = 43; bit >= 0; --bit){
            const u64 cand = T | (1ull << bit);
            int c = 0;
            #pragma unroll
            for (int u=0; u<10; ++u) c += (mkey[u] >= cand) ? 1 : 0;
            c += __shfl_xor(c, 1); c += __shfl_xor(c, 2); c += __shfl_xor(c, 4);
            c += __shfl_xor(c, 8); c += __shfl_xor(c, 16);
            if (c >= TK) T = cand;
        }
        // compact the exactly-128 keys >= T via 32-wide exclusive scan (no atomics)
        int mycnt = 0;
        #pragma unroll
        for (int u=0; u<10; ++u) mycnt += (mkey[u] >= T) ? 1 : 0;
        int pre = mycnt;
        #pragma unroll
        for (int off=1; off<32; off<<=1){
            const int v = __shfl_up(pre, off, 32);
            if (s >= off) pre += v;
        }
        int base = pre - mycnt;
        #pragma unroll
        for (int u=0; u<10; ++u){
            if (mkey[u] >= T){
                up.sel.keyhi[r][base] = (u32)(mkey[u] >> 13);
                up.sel.kcol[r][base]  = (u16)(8191 - (int)(mkey[u] & 8191u));
                ++base;
            }
        }
        // rerank the 128 into exact (val desc, col asc) order (wave-internal ordering)
        u64 rk[4]; int rr[4];
        #pragma unroll
        for (int u2=0; u2<4; ++u2){
            const int idx = s + (u2<<5);
            rk[u2] = ((u64)up.sel.keyhi[r][idx] << 13) | (u64)(8191 - (int)up.sel.kcol[r][idx]);
            rr[u2] = 0;
        }
        for (int j=0; j<TK; ++j){
            const u64 kj = ((u64)up.sel.keyhi[r][j] << 13) | (u64)(8191 - (int)up.sel.kcol[r][j]);
            #pragma unroll
            for (int u2=0; u2<4; ++u2) rr[u2] += (kj > rk[u2]) ? 1 : 0;
        }
        #pragma unroll
        for (int u2=0; u2<4; ++u2){
            up.sel.keyhi[r][rr[u2]] = (u32)(rk[u2] >> 13);
            up.sel.kcol[r][rr[u2]]  = (u16)(8191 - (int)(rk[u2] & 8191u));
        }
    }
    __syncthreads();

    // ---- phases V+K: 2 passes of 16 rows, 32 thr/row, 4 candidates/thread ----
    for (int half=0; half<2; ++half){
        const int r = (t >> 5) + half*16;
        const int s = t & 31;
        const int i = i0 + r;
        const float cx = coords[((size_t)b*NN + i)*3 + 0];
        const float cy = coords[((size_t)b*NN + i)*3 + 1];
        const float cz = coords[((size_t)b*NN + i)*3 + 2];
        float wdx[4], wdy[4], wdz[4], wvl[4], wdist[4];
        #pragma unroll
        for (int u=0; u<4; ++u){
            const int w = s + (u<<5);
            const u32 kh = up.sel.keyhi[r][w];
            const int col = (int)up.sel.kcol[r][w];
            const float val = key2f(kh);
            const float* pp = xyz2 + ((size_t)b*NN + col)*3;
            const float dx = pp[0]-cx, dy = pp[1]-cy, dz = pp[2]-cz;
            wdist[u] = dx*dx + dy*dy + dz*dz;
            wdx[u]=dx; wdy[u]=dy; wdz[u]=dz; wvl[u]=val;
            #pragma unroll
            for (int lvl=0; lvl<3; ++lvl){
                const float rs = 0.25f * (float)(1<<lvl);
                const float fx = rintf(dx/rs), fy = rintf(dy/rs), fz = rintf(dz/rs);
                if (fabsf(fx)<=1.f && fabsf(fy)<=1.f && fabsf(fz)<=1.f){
                    const int bin = lvl*27 + ((int)fx+1)*9 + ((int)fy+1)*3 + ((int)fz+1);
                    // count in bits 24+, sum(val*2^13) in bits 0-23 (vals>0; 128*8*8192 < 2^24)
                    atomicAdd(&vboth[r][bin], (1u<<24) | (u32)lrintf(val*8192.f));
                }
            }
        }
        // knn rank via half-wave broadcast (rows are 32-lane groups)
        const int rbase = lane & 32;
        int rank[4] = {0,0,0,0};
        #pragma unroll
        for (int u2=0; u2<4; ++u2){
            #pragma unroll
            for (int jj=0; jj<32; ++jj){
                const float o = __shfl(wdist[u2], rbase + jj);
                const int j = jj + (u2<<5);
                #pragma unroll
                for (int u=0; u<4; ++u)
                    rank[u] += (o < wdist[u] || (o == wdist[u] && j < s + (u<<5))) ? 1 : 0;
            }
        }
        float m1[4] = {0.f,0.f,0.f,0.f};
        float m2[16];
        #pragma unroll
        for (int q=0;q<16;q++) m2[q]=0.f;
        #pragma unroll
        for (int u=0; u<4; ++u){
            if (rank[u] < KNNK){
                const float kv[4] = {wvl[u], wdx[u], wdy[u], wdz[u]};
                uint2 kw;
                kw.x = (u32)f2h_bits(kv[0]) | ((u32)f2h_bits(kv[1]) << 16);
                kw.y = (u32)f2h_bits(kv[2]) | ((u32)f2h_bits(kv[3]) << 16);
                wskin[((size_t)b*NN + i)*KNNK + rank[u]] = kw;
                #pragma unroll
                for (int a2=0;a2<4;a2++){
                    m1[a2] += kv[a2];
                    #pragma unroll
                    for (int b2=0;b2<4;b2++) m2[a2*4+b2] += kv[a2]*kv[b2];
                }
            }
        }
        #pragma unroll
        for (int q=0; q<20; ++q){
            i64 v = llrintf(((q<4) ? m1[q] : m2[q-4]) * 1048576.f);
            #pragma unroll
            for (int off=1; off<64; off<<=1) v += __shfl_xor(v, off);
            if (lane == 0){
                if (q < 4) atomicAdd(&wk1[q], (u64)v);
                else       atomicAdd(&wk2[q-4], (u64)v);
            }
        }
    }
    __syncthreads();

    // ---- w1 -> LDS (select space dead) + voxn finalize (in-place) ----
    for (int idx=t; idx<128*81; idx+=512) up.w1s[idx] = w1[idx];
    for (int z=t; z<32*81; z+=512){
        const u32 k = ((u32*)vboth)[z];
        const float vv = (float)(k & 0xFFFFFFu) * (1.f/8192.f);
        const float c = fmaxf((float)(k >> 24), 1.f);
        ((float*)vboth)[z] = vv / c;
    }
    __syncthreads();

    // ---- phase H: h = b1 + w1*voxn ; store f16 ; group stats ----
    {
        const int r = t >> 4, cg = t & 15;   // 32 rows x 16 channel-groups of 8
        const int i = i0 + r;
        const float* voxnp = (const float*)&vboth[0][0];
        float h8[8];
        #pragma unroll
        for (int i2=0;i2<8;i2++) h8[i2] = b1[cg*8+i2];
        for (int j=0; j<81; ++j){
            const float vj = voxnp[r*81 + j];
            #pragma unroll
            for (int i2=0;i2<8;i2++) h8[i2] = fmaf(up.w1s[(cg*8+i2)*81 + j], vj, h8[i2]);
        }
        uint4 hv4;
        hv4.x = (u32)f2h_bits(h8[0]) | ((u32)f2h_bits(h8[1])<<16);
        hv4.y = (u32)f2h_bits(h8[2]) | ((u32)f2h_bits(h8[3])<<16);
        hv4.z = (u32)f2h_bits(h8[4]) | ((u32)f2h_bits(h8[5])<<16);
        hv4.w = (u32)f2h_bits(h8[6]) | ((u32)f2h_bits(h8[7])<<16);
        ((uint4*)wsh)[((size_t)(b*NN + i)*128 + cg*8) >> 3] = hv4;
        i64 s1 = 0, s2 = 0;
        #pragma unroll
        for (int i2=0;i2<8;i2++){
            s1 += llrintf(h8[i2]*1048576.f);
            s2 += llrintf(h8[i2]*h8[i2]*1048576.f);
        }
        s1 += __shfl_xor(s1, 1);  s2 += __shfl_xor(s2, 1);
        s1 += __shfl_xor(s1, 16); s2 += __shfl_xor(s2, 16);
        s1 += __shfl_xor(s1, 32); s2 += __shfl_xor(s2, 32);
        if (((lane & 1) == 0) && (lane >> 4) == 0){
            atomicAdd(&wgo[cg>>1], (u64)s1);
            atomicAdd(&wgq[cg>>1], (u64)s2);
        }
    }
    __syncthreads();

    if (t < 8){ atomicAdd(&stats[b*8 + t], wgo[t]); atomicAdd(&stats[16 + b*8 + t], wgq[t]); }
    if (t < 4){ atomicAdd(&stats[32 + b*4 + t], wk1[t]); }
    if (t < 16){ atomicAdd(&stats[40 + b*16 + t], wk2[t]); }
}

// ---------------- K2: finalize GN statistics ----------------
__global__ void k2_stats(const u64* __restrict__ stats, float* __restrict__ fstats,
                         const float* __restrict__ kcw, const float* __restrict__ kcb)
{
    const int t = threadIdx.x;
    if (t < 16){
        const double S = (double)(i64)stats[t];
        const double Q = (double)(i64)stats[16+t];
        const double cnt = 16.0*8192.0;
        const double mean = S / 1048576.0 / cnt;
        const double var  = Q / 1048576.0 / cnt - mean*mean;
        fstats[t]    = (float)mean;
        fstats[16+t] = (float)(1.0/sqrt(var + 1e-5));
    }
    if (t >= 32 && t < 48){
        const int u = t - 32;
        const int b = u >> 3, g = u & 7;
        double M1[4], M2[4][4];
        for (int a=0;a<4;a++) M1[a] = (double)(i64)stats[32 + b*4 + a] / 1048576.0;
        for (int a=0;a<4;a++) for (int c=0;c<4;c++)
            M2[a][c] = (double)(i64)stats[40 + b*16 + a*4 + c] / 1048576.0;
        const double cnt = 8192.0*32.0;
        double SUM=0.0, SSQ=0.0;
        for (int c = g*8; c < g*8+8; ++c){
            double wv[4]; for (int a=0;a<4;a++) wv[a] = (double)kcw[c*4+a];
            const double bc = (double)kcb[c];
            double sc = bc*cnt, qc = bc*bc*cnt;
            for (int a=0;a<4;a++){
                sc += wv[a]*M1[a];
                qc += 2.0*bc*wv[a]*M1[a];
                for (int e=0;e<4;e++) qc += wv[a]*wv[e]*M2[a][e];
            }
            SUM += sc; SSQ += qc;
        }
        const double denom = 8.0*cnt;
        const double mean = SUM/denom;
        const double var  = SSQ/denom - mean*mean;
        fstats[32+u] = (float)mean;
        fstats[48+u] = (float)(1.0/sqrt(var + 1e-5));
    }
}

// ---------------- K3a: GN + PReLU + W2 (vox branch) ----------------
__global__ __launch_bounds__(256) void k3a_vox(
    const u16* __restrict__ wsh, const float* __restrict__ fstats,
    const float* __restrict__ gnw, const float* __restrict__ gnb,
    const float* __restrict__ pr, const float* __restrict__ w2,
    const float* __restrict__ b2, float* __restrict__ out)
{
    __shared__ float p[16][128];
    __shared__ float w2s[64][129];
    const int t = threadIdx.x;
    const int base = blockIdx.x * 16;
    const int b = base >> 13;
    for (int u=t; u<64*128; u+=256) w2s[u>>7][u&127] = w2[u];
    const float a = pr[0];
    for (int u=t; u<16*128; u+=256){
        const int pt=u>>7, c=u&127, g=c>>4;
        const float hv = h2f(wsh[(size_t)(base+pt)*128 + c]);
        const float hn = (hv - fstats[b*8+g])*fstats[16+b*8+g]*gnw[c] + gnb[c];
        p[pt][c] = hn>=0.f ? hn : a*hn;
    }
    __syncthreads();
    const int o = t & 63, wv = t >> 6;
    float acc0=b2[o], acc1=acc0, acc2=acc0, acc3=acc0;
    for (int c=0;c<128;c++){
        const float w = w2s[o][c];
        acc0 = fmaf(w, p[wv*4+0][c], acc0);
        acc1 = fmaf(w, p[wv*4+1][c], acc1);
        acc2 = fmaf(w, p[wv*4+2][c], acc2);
        acc3 = fmaf(w, p[wv*4+3][c], acc3);
    }
    const float4 res = {acc0,acc1,acc2,acc3};
    *(float4*)&out[((size_t)b*64 + o)*NN + (base & (NN-1)) + wv*4] = res;
}

// ---------------- K3b: knn conv + GN + PReLU + maxpool + ko ----------------
__global__ __launch_bounds__(256) void k3b_knn(
    const uint2* __restrict__ wskin, const float* __restrict__ fstats,
    const float* __restrict__ kcw, const float* __restrict__ kcb,
    const float* __restrict__ gnw, const float* __restrict__ gnb,
    const float* __restrict__ pr, const float* __restrict__ kow,
    const float* __restrict__ kob, float* __restrict__ out)
{
    __shared__ float skin[16][KNNK*4+4];
    __shared__ float kml[16][65];
    __shared__ float kos[64][65];
    const int t = threadIdx.x;
    const int base = blockIdx.x * 16;
    const int b = base >> 13;
    for (int v=t; v<16*KNNK; v+=256){
        const int pt = v>>5, q = v&31;
        const uint2 kw = wskin[(size_t)(base+pt)*KNNK + q];
        skin[pt][q*4+0] = h2f((u16)(kw.x & 0xFFFF));
        skin[pt][q*4+1] = h2f((u16)(kw.x >> 16));
        skin[pt][q*4+2] = h2f((u16)(kw.y & 0xFFFF));
        skin[pt][q*4+3] = h2f((u16)(kw.y >> 16));
    }
    for (int u=t; u<4096; u+=256) kos[u>>6][u&63] = kow[u];
    __syncthreads();
    const float a = pr[0];
    {
        const int pt = t>>4, cb = (t&15)*4;
        #pragma unroll
        for (int cc=0; cc<4; ++cc){
            const int c = cb+cc, g = c>>3;
            const float mean = fstats[32+b*8+g], rstd = fstats[48+b*8+g];
            const float gw = rstd*gnw[c], gb = gnb[c]-mean*gw;
            const float w0=kcw[c*4], w1v=kcw[c*4+1], w2v=kcw[c*4+2], w3=kcw[c*4+3], bc=kcb[c];
            float mx = -3.0e38f;
            for (int kk=0;kk<KNNK;kk++){
                const float4 sv = *(const float4*)&skin[pt][kk*4];
                float kf = fmaf(w0,sv.x, fmaf(w1v,sv.y, fmaf(w2v,sv.z, fmaf(w3,sv.w, bc))));
                float hn = kf*gw + gb;
                hn = hn>=0.f ? hn : a*hn;
                mx = fmaxf(mx, hn);
            }
            kml[pt][c] = mx;
        }
    }
    __syncthreads();
    const int o = t & 63, wv = t >> 6;
    float acc0=kob[o], acc1=acc0, acc2=acc0, acc3=acc0;
    for (int c=0;c<64;c++){
        const float w = kos[o][c];
        acc0 = fmaf(w, kml[wv*4+0][c], acc0);
        acc1 = fmaf(w, kml[wv*4+1][c], acc1);
        acc2 = fmaf(w, kml[wv*4+2][c], acc2);
        acc3 = fmaf(w, kml[wv*4+3][c], acc3);
    }
    float* op = &out[((size_t)b*64 + o)*NN + (base & (NN-1)) + wv*4];
    float4 cur = *(float4*)op;
    cur.x += acc0; cur.y += acc1; cur.z += acc2; cur.w += acc3;
    *(float4*)op = cur;
}

extern "C" void kernel_launch(void* const* d_in, const int* in_sizes, int n_in,
                              void* d_out, int out_size, void* d_ws, size_t ws_size,
                              hipStream_t stream)
{
    const float* fmap1   = (const float*)d_in[0];
    const float* fmap2   = (const float*)d_in[1];
    const float* xyz2    = (const float*)d_in[2];
    const float* coords  = (const float*)d_in[3];
    const float* oc_w1   = (const float*)d_in[4];
    const float* oc_b1   = (const float*)d_in[5];
    const float* oc_gn_w = (const float*)d_in[6];
    const float* oc_gn_b = (const float*)d_in[7];
    const float* oc_pr   = (const float*)d_in[8];
    const float* oc_w2   = (const float*)d_in[9];
    const float* oc_b2   = (const float*)d_in[10];
    const float* kc_w    = (const float*)d_in[11];
    const float* kc_b    = (const float*)d_in[12];
    const float* kc_gn_w = (const float*)d_in[13];
    const float* kc_gn_b = (const float*)d_in[14];
    const float* kc_pr   = (const float*)d_in[15];
    const float* ko_w    = (const float*)d_in[16];
    const float* ko_b    = (const float*)d_in[17];

    char* ws = (char*)d_ws;
    f16*   f2p    = (f16*)ws;
    u16*   wsh    = (u16*)(ws + (size_t)8*1024*1024);
    uint2* wskin  = (uint2*)(ws + (size_t)12*1024*1024);
    u64*   stats  = (u64*) (ws + (size_t)16*1024*1024);
    float* fstats = (float*)(ws + (size_t)16*1024*1024 + 1024);
    float* out    = (float*)d_out;

    k0_zero<<<dim3(1), dim3(128), 0, stream>>>(stats);
    k0b_pack<<<dim3(1024), dim3(256), 0, stream>>>(fmap2, f2p);
    k1_corr_topk<<<dim3(512), dim3(512), 0, stream>>>(
        fmap1, f2p, xyz2, coords, oc_w1, oc_b1, wsh, wskin, stats);
    k2_stats<<<dim3(1), dim3(64), 0, stream>>>(stats, fstats, kc_w, kc_b);
    k3a_vox<<<dim3(1024), dim3(256), 0, stream>>>(
        wsh, fstats, oc_gn_w, oc_gn_b, oc_pr, oc_w2, oc_b2, out);
    k3b_knn<<<dim3(1024), dim3(256), 0, stream>>>(
        wskin, fstats, kc_w, kc_b, kc_gn_w, kc_gn_b, kc_pr, ko_w, ko_b, out);
}